// Round 1
// baseline (1458.912 us; speedup 1.0000x reference)
//
#include <hip/hip_runtime.h>

#define TT 2048
#define BB 64

__device__ __forceinline__ float frcp(float x) { return __builtin_amdgcn_rcpf(x); }
__device__ __forceinline__ float fsig(float x) { return frcp(1.f + __expf(-x)); }
__device__ __forceinline__ float ftan(float x) { return 1.f - 2.f * frcp(1.f + __expf(2.f * x)); }

// G[(b*Tc+tt)*256 + g] = sum_k X[b, t0+tt, k] * W_ih[g, k] + b_ih[g] + b_hh[g]
// Tiled fp32 GEMM: M = 64*Tc (rows b*Tc+tt), N = 256 (gates), K = 256.
// grid = (Tc, 4), block = 256. Tile 64x64, BK=32.
__global__ __launch_bounds__(256) void gates_gemm(const float* __restrict__ X,
                                                  const float* __restrict__ W,
                                                  const float* __restrict__ bih,
                                                  const float* __restrict__ bhh,
                                                  float* __restrict__ G,
                                                  int t0, int Tc) {
  __shared__ __align__(16) float As[32][64];  // As[k][m]
  __shared__ __align__(16) float Bs[32][64];  // Bs[k][n]
  const int tid = threadIdx.x;
  const int m0 = blockIdx.x * 64;   // chunk-row base; Tc%64==0 so tile stays in one b
  const int n0 = blockIdx.y * 64;
  const int bb = m0 / Tc;
  const int tt0 = m0 - bb * Tc;
  const int tx = tid & 15, ty = tid >> 4;
  const int r  = tid >> 2;          // 0..63 (row within tile)
  const int kq = (tid & 3) * 8;     // 0,8,16,24 (k-octet)
  const float* xrow = X + ((size_t)(bb * TT + t0 + tt0 + r)) * 256 + kq;
  const float* wrow = W + (size_t)(n0 + r) * 257 + kq;
  float acc[4][4] = {};
  for (int k0 = 0; k0 < 256; k0 += 32) {
    float4 a0 = *reinterpret_cast<const float4*>(xrow + k0);
    float4 a1 = *reinterpret_cast<const float4*>(xrow + k0 + 4);
    float bv[8];
#pragma unroll
    for (int u = 0; u < 8; ++u) bv[u] = wrow[k0 + u];
    if (k0 != 0) __syncthreads();   // prior compute done before overwriting LDS
    As[kq+0][r]=a0.x; As[kq+1][r]=a0.y; As[kq+2][r]=a0.z; As[kq+3][r]=a0.w;
    As[kq+4][r]=a1.x; As[kq+5][r]=a1.y; As[kq+6][r]=a1.z; As[kq+7][r]=a1.w;
#pragma unroll
    for (int u = 0; u < 8; ++u) Bs[kq+u][r] = bv[u];
    __syncthreads();
#pragma unroll
    for (int kk = 0; kk < 32; ++kk) {
      float4 av = *reinterpret_cast<const float4*>(&As[kk][ty*4]);
      float4 bw = *reinterpret_cast<const float4*>(&Bs[kk][tx*4]);
      const float aa[4] = {av.x, av.y, av.z, av.w};
      const float bbv[4] = {bw.x, bw.y, bw.z, bw.w};
#pragma unroll
      for (int i = 0; i < 4; ++i)
#pragma unroll
        for (int j = 0; j < 4; ++j) acc[i][j] += aa[i] * bbv[j];
    }
  }
  const int col = n0 + tx * 4;
  float bsum[4];
#pragma unroll
  for (int j = 0; j < 4; ++j) bsum[j] = bih[col + j] + bhh[col + j];
#pragma unroll
  for (int i = 0; i < 4; ++i) {
    float4 o;
    o.x = acc[i][0] + bsum[0];
    o.y = acc[i][1] + bsum[1];
    o.z = acc[i][2] + bsum[2];
    o.w = acc[i][3] + bsum[3];
    *reinterpret_cast<float4*>(&G[(size_t)(m0 + ty*4 + i) * 256 + col]) = o;
  }
}

// P[b*Tc+tt] = x[b, t0+tt, :] @ w21 + bias2.  One wave per row, 4 rows/block.
__global__ __launch_bounds__(256) void pz_kernel(const float* __restrict__ X,
                                                 const float* __restrict__ w21,
                                                 const float* __restrict__ bias2,
                                                 float* __restrict__ P,
                                                 int t0, int Tc) {
  const int r = blockIdx.x * 4 + (threadIdx.x >> 6);
  const int lane = threadIdx.x & 63;
  const int bb = r / Tc;
  const int tt = r - bb * Tc;
  const float4 xv = *reinterpret_cast<const float4*>(
      &X[((size_t)(bb * TT + t0 + tt)) * 256 + lane * 4]);
  const float4 wv = *reinterpret_cast<const float4*>(&w21[lane * 4]);
  float s = xv.x*wv.x + xv.y*wv.y + xv.z*wv.z + xv.w*wv.w;
#pragma unroll
  for (int o = 32; o; o >>= 1) s += __shfl_xor(s, o);
  if (lane == 0) P[r] = s + bias2[0];
}

// Serial recurrence: one WG per batch row, thread g owns gate g.
__global__ __launch_bounds__(256) void lstm_seq(const float* __restrict__ G,
                                                const float* __restrict__ P,
                                                const float* __restrict__ Wih,
                                                const float* __restrict__ Whh,
                                                const float* __restrict__ w22,
                                                float* __restrict__ Z,
                                                float* __restrict__ hq,
                                                float* __restrict__ cq,
                                                int t0, int Tc) {
  const int b = blockIdx.x;
  const int g = threadIdx.x;
  const int lane = g & 63;
  __shared__ __align__(16) float h_s[64];
  __shared__ float act_s[256];
  float wh[64];
#pragma unroll
  for (int j = 0; j < 64; j += 4) {
    float4 v = *reinterpret_cast<const float4*>(&Whh[(size_t)g * 64 + j]);
    wh[j] = v.x; wh[j+1] = v.y; wh[j+2] = v.z; wh[j+3] = v.w;
  }
  const float wihL = Wih[(size_t)g * 257 + 256];
  const float w22r = w22[lane];
  float c = 0.f;
  if (g < 64) {
    float hv = 0.f;
    if (t0 != 0) { hv = hq[b * 64 + g]; c = cq[b * 64 + g]; }
    h_s[g] = hv;
  }
  __syncthreads();
  const float* Gb = G + (size_t)b * Tc * 256 + g;
  const float* Pb = P + (size_t)b * Tc;
  float* Zb = Z + (size_t)b * TT + t0;
  float gx = Gb[0];
  float p0 = Pb[0];
  for (int tt = 0; tt < Tc; ++tt) {
    const int ttn = (tt + 1 < Tc) ? tt + 1 : tt;   // branchless prefetch
    const float gx_n = Gb[(size_t)ttn * 256];
    const float p0_n = Pb[ttn];
    // pz: each wave redundantly reduces h*w22 over its own 64 lanes (no extra barrier)
    float pv = h_s[lane] * w22r;
#pragma unroll
    for (int o = 32; o; o >>= 1) pv += __shfl_xor(pv, o);
    const float pz = fsig(pv + p0);
    // dot(h, Whh[g,:]) — h broadcast from LDS, weights in VGPRs, 4 accumulators
    float a0 = 0.f, a1 = 0.f, a2 = 0.f, a3 = 0.f;
#pragma unroll
    for (int j = 0; j < 64; j += 4) {
      float4 hv = *reinterpret_cast<const float4*>(&h_s[j]);
      a0 += hv.x * wh[j]; a1 += hv.y * wh[j+1]; a2 += hv.z * wh[j+2]; a3 += hv.w * wh[j+3];
    }
    const float pre = gx + pz * wihL + ((a0 + a1) + (a2 + a3));
    act_s[g] = ((g >> 6) == 2) ? ftan(pre) : fsig(pre);  // gate 2 (g) is tanh; wave-uniform branch
    if (g == 0) Zb[tt] = pz;
    __syncthreads();
    if (g < 64) {
      const float iv = act_s[g], fv = act_s[64+g], gv = act_s[128+g], ov = act_s[192+g];
      c = fv * c + iv * gv;
      h_s[g] = ov * ftan(c);
    }
    __syncthreads();
    gx = gx_n; p0 = p0_n;
  }
  if (g < 64) { hq[b * 64 + g] = h_s[g]; cq[b * 64 + g] = c; }
}

// Fully-inline fallback (only if d_ws is too small for even a 64-step chunk).
__global__ __launch_bounds__(256) void lstm_fallback(const float* __restrict__ X,
    const float* __restrict__ w21, const float* __restrict__ w22,
    const float* __restrict__ bias2, const float* __restrict__ Wih,
    const float* __restrict__ Whh, const float* __restrict__ bih,
    const float* __restrict__ bhh, float* __restrict__ Z) {
  const int b = blockIdx.x;
  const int g = threadIdx.x;
  const int lane = g & 63;
  __shared__ __align__(16) float h_s[64];
  __shared__ float act_s[256];
  __shared__ __align__(16) float x_s[256];
  __shared__ __align__(16) float w21_s[256];
  float wh[64];
#pragma unroll
  for (int j = 0; j < 64; j += 4) {
    float4 v = *reinterpret_cast<const float4*>(&Whh[(size_t)g*64 + j]);
    wh[j]=v.x; wh[j+1]=v.y; wh[j+2]=v.z; wh[j+3]=v.w;
  }
  const float wihL = Wih[(size_t)g*257 + 256];
  const float bias = bih[g] + bhh[g];
  const float b2 = bias2[0];
  const float w22r = w22[lane];
  w21_s[g] = w21[g];
  if (g < 64) h_s[g] = 0.f;
  float c = 0.f;
  __syncthreads();
  const float* Wr = Wih + (size_t)g * 257;
  for (int t = 0; t < TT; ++t) {
    x_s[g] = X[((size_t)b*TT + t)*256 + g];
    __syncthreads();
    float pv = h_s[lane] * w22r;
    {
      const float4 xq = *reinterpret_cast<const float4*>(&x_s[lane*4]);
      const float4 wq = *reinterpret_cast<const float4*>(&w21_s[lane*4]);
      pv += xq.x*wq.x + xq.y*wq.y + xq.z*wq.z + xq.w*wq.w;
    }
#pragma unroll
    for (int o = 32; o; o >>= 1) pv += __shfl_xor(pv, o);
    const float pz = fsig(pv + b2);
    float a0=0.f, a1=0.f, a2=0.f, a3=0.f;
#pragma unroll
    for (int j = 0; j < 64; j += 4) {
      float4 hv = *reinterpret_cast<const float4*>(&h_s[j]);
      a0 += hv.x*wh[j]; a1 += hv.y*wh[j+1]; a2 += hv.z*wh[j+2]; a3 += hv.w*wh[j+3];
    }
    float xd0=0.f, xd1=0.f, xd2=0.f, xd3=0.f;
    for (int k = 0; k < 256; k += 4) {
      const float4 xq = *reinterpret_cast<const float4*>(&x_s[k]);
      xd0 += xq.x*Wr[k]; xd1 += xq.y*Wr[k+1]; xd2 += xq.z*Wr[k+2]; xd3 += xq.w*Wr[k+3];
    }
    const float pre = bias + pz*wihL + ((a0+a1)+(a2+a3)) + ((xd0+xd1)+(xd2+xd3));
    act_s[g] = ((g >> 6) == 2) ? ftan(pre) : fsig(pre);
    if (g == 0) Z[(size_t)b*TT + t] = pz;
    __syncthreads();
    if (g < 64) {
      const float iv = act_s[g], fv = act_s[64+g], gv = act_s[128+g], ov = act_s[192+g];
      c = fv*c + iv*gv;
      h_s[g] = ov * ftan(c);
    }
    __syncthreads();
  }
}

extern "C" void kernel_launch(void* const* d_in, const int* in_sizes, int n_in,
                              void* d_out, int out_size, void* d_ws, size_t ws_size,
                              hipStream_t stream) {
  const float* X     = (const float*)d_in[0];  // [64,2048,256]
  const float* w21   = (const float*)d_in[1];  // [256]
  const float* w22   = (const float*)d_in[2];  // [64]
  const float* bias2 = (const float*)d_in[3];  // [1]
  const float* Wih   = (const float*)d_in[4];  // [256,257]
  const float* Whh   = (const float*)d_in[5];  // [256,64]
  const float* bih   = (const float*)d_in[6];  // [256]
  const float* bhh   = (const float*)d_in[7];  // [256]
  float* Z = (float*)d_out;                    // [64,2048]

  // Pick the largest time-chunk that fits in workspace.
  int Tc = 0;
  for (int cand = 2048; cand >= 64; cand >>= 1) {
    size_t need = (size_t)cand * (64*256*4 + 64*4) + 2*64*64*4;
    if (ws_size >= need) { Tc = cand; break; }
  }
  if (Tc == 0) {
    lstm_fallback<<<dim3(64), dim3(256), 0, stream>>>(X, w21, w22, bias2, Wih, Whh, bih, bhh, Z);
    return;
  }
  float* Gbuf = (float*)d_ws;                       // [64*Tc, 256]
  float* Pbuf = Gbuf + (size_t)64 * Tc * 256;       // [64*Tc]
  float* hq   = Pbuf + (size_t)64 * Tc;             // [64,64]
  float* cq   = hq + 64 * 64;                       // [64,64]
  for (int t0 = 0; t0 < 2048; t0 += Tc) {
    gates_gemm<<<dim3(Tc, 4), dim3(256), 0, stream>>>(X, Wih, bih, bhh, Gbuf, t0, Tc);
    pz_kernel<<<dim3(16 * Tc), dim3(256), 0, stream>>>(X, w21, bias2, Pbuf, t0, Tc);
    lstm_seq<<<dim3(64), dim3(256), 0, stream>>>(Gbuf, Pbuf, Wih, Whh, w22, Z, hq, cq, t0, Tc);
  }
}